// Round 3
// baseline (34334.326 us; speedup 1.0000x reference)
//
#include <hip/hip_runtime.h>
#include <math.h>

#define HID    512
#define BATCH  512
#define TIN    512
#define TOUT   128
#define FOUR_H 2048
#define STEPS  (TIN + TOUT)
#define LDS_STRIDE 520   // elements; 1040 B/row: 16B-aligned, spreads banks uniformly

typedef __bf16 bf16x8 __attribute__((ext_vector_type(8)));
typedef float floatx4 __attribute__((ext_vector_type(4)));

__device__ __forceinline__ float fsig(float x) {
    // 1/(1+e^-x); exp->inf gives 0, exp->0 gives 1 (correct saturation)
    return __builtin_amdgcn_rcpf(1.0f + __expf(-x));
}
__device__ __forceinline__ float ftanh(float x) {
    // 1 - 2/(e^{2x}+1); x->+inf: 1, x->-inf: -1
    return 1.0f - 2.0f * __builtin_amdgcn_rcpf(1.0f + __expf(2.0f * x));
}

// ---------- prep: pack Whh (4H x H fp32, row r = g*512+j) into m' = 4*j + g
// order, split into bf16 hi/lo planes. (verified in R2: absmax 1.2e-7)
__global__ __launch_bounds__(256) void pack_w(
    const float* __restrict__ W, __bf16* __restrict__ outHi, __bf16* __restrict__ outLo)
{
    int tid = blockIdx.x * 256 + threadIdx.x;     // 131072 threads
    int mp  = tid >> 6;
    int kg  = (tid & 63) * 8;
    int g   = mp & 3;
    int j   = mp >> 2;
    int r   = g * HID + j;
    const float* src = W + (size_t)r * HID + kg;
    __bf16* dh = outHi + (size_t)mp * HID + kg;
    __bf16* dl = outLo + (size_t)mp * HID + kg;
    #pragma unroll
    for (int i = 0; i < 8; ++i) {
        float x = src[i];
        __bf16 hi = (__bf16)x;
        dh[i] = hi;
        dl[i] = (__bf16)(x - (float)hi);
    }
}

__global__ __launch_bounds__(256) void pack_v(
    const float* __restrict__ Wih, const float* __restrict__ b,
    float* __restrict__ WihP, float* __restrict__ bP)
{
    int mp = blockIdx.x * 256 + threadIdx.x;      // 2048 threads
    int g  = mp & 3;
    int j  = mp >> 2;
    int r  = g * HID + j;
    WihP[mp] = Wih[r];
    bP[mp]   = b[r];
}

// inputs [b][t] -> inputsT [t][b] (coalesced writes)
__global__ __launch_bounds__(256) void transpose_in(
    const float* __restrict__ in, float* __restrict__ outT)
{
    int idx = blockIdx.x * 256 + threadIdx.x;     // 262144 threads
    int t = idx >> 9, b = idx & 511;
    outT[idx] = in[(size_t)b * TIN + t];
}

// ---------- the persistent kernel ----------
// grid 256 = 32 mx (weight-row groups) x 8 by (batch groups); block 256 = 4 waves.
// by = blockIdx.x & 7 so a by-group likely maps to one XCD (locality heuristic only).
__global__ __launch_bounds__(256, 1) void lstm_persistent(
    const __bf16* __restrict__ AencHi, const __bf16* __restrict__ AencLo,
    const __bf16* __restrict__ AdecHi, const __bf16* __restrict__ AdecLo,
    const float* __restrict__ WihPenc, const float* __restrict__ biasPenc,
    const float* __restrict__ WihPdec, const float* __restrict__ biasPdec,
    const float* __restrict__ inputsT,
    const float* __restrict__ linW, const float* __restrict__ linb,
    __bf16* __restrict__ h0hi, __bf16* __restrict__ h0lo,
    __bf16* __restrict__ h1hi, __bf16* __restrict__ h1lo,
    float* __restrict__ xacc,        // [3][BATCH], rotating decoder-feedback accum
    int* __restrict__ barrier_ws,    // [1024] ints: arrive at by*32, phase at 512+by*32
    float* __restrict__ out)         // [BATCH][TOUT]
{
    extern __shared__ char smem[];
    __bf16* Ahi = (__bf16*)smem;                       // [64][LDS_STRIDE]
    __bf16* Alo = Ahi + 64 * LDS_STRIDE;
    float*  xred = (float*)(Alo + 64 * LDS_STRIDE);    // [64]

    const int tid  = threadIdx.x;
    const int lane = tid & 63;
    const int w    = tid >> 6;
    const int lr   = lane & 15;
    const int lq   = lane >> 4;
    const int by   = blockIdx.x & 7;
    const int mx   = blockIdx.x >> 3;
    const int nbase = by * 64;
    const int mrow0 = mx * 64;
    const int m0    = mrow0 + w * 16 + lq * 4;   // lane's 4 m' rows = 4 gates of j
    const int j     = m0 >> 2;

    // per-lane constants, loaded once for all 640 steps
    const floatx4 wihE = *(const floatx4*)(WihPenc + m0);
    const floatx4 bE   = *(const floatx4*)(biasPenc + m0);
    const floatx4 wihD = *(const floatx4*)(WihPdec + m0);
    const floatx4 bD   = *(const floatx4*)(biasPdec + m0);
    const float lw = linW[j];
    const float lb = linb[0];

    int bn[4];
    #pragma unroll
    for (int nt = 0; nt < 4; ++nt) bn[nt] = nbase + nt * 16 + lr;

    // stage encoder weights into LDS (once)
    for (int i = tid; i < 4096; i += 256) {
        int r = i >> 6, c8 = (i & 63) << 3;
        *(bf16x8*)(Ahi + r * LDS_STRIDE + c8) = *(const bf16x8*)(AencHi + (size_t)(mrow0 + r) * HID + c8);
        *(bf16x8*)(Alo + r * LDS_STRIDE + c8) = *(const bf16x8*)(AencLo + (size_t)(mrow0 + r) * HID + c8);
    }
    __syncthreads();

    float creg[4] = {0.f, 0.f, 0.f, 0.f};   // cell state, register-resident for all steps

    int* arrive = barrier_ws + by * 32;       // 128 B apart per group
    int* phase  = barrier_ws + 512 + by * 32;

    const __bf16* aHi_p = Ahi + (w * 16 + lr) * LDS_STRIDE + lq * 8;
    const __bf16* aLo_p = Alo + (w * 16 + lr) * LDS_STRIDE + lq * 8;

    for (int s = 0; s < STEPS; ++s) {
        const bool dec = (s >= TIN);
        const int  t   = s - TIN;

        if (s == TIN) {   // swap to decoder weights (prev iter ended with __syncthreads)
            for (int i = tid; i < 4096; i += 256) {
                int r = i >> 6, c8 = (i & 63) << 3;
                *(bf16x8*)(Ahi + r * LDS_STRIDE + c8) = *(const bf16x8*)(AdecHi + (size_t)(mrow0 + r) * HID + c8);
                *(bf16x8*)(Alo + r * LDS_STRIDE + c8) = *(const bf16x8*)(AdecLo + (size_t)(mrow0 + r) * HID + c8);
            }
            __syncthreads();
        }

        const __bf16* hinhi = (s & 1) ? h1hi : h0hi;
        const __bf16* hinlo = (s & 1) ? h1lo : h0lo;
        __bf16* houthi = (s & 1) ? h0hi : h1hi;
        __bf16* houtlo = (s & 1) ? h0lo : h1lo;

        // ---- x_t for this lane's 4 batches; decoder bookkeeping ----
        float xq[4];
        if (dec) {
            if (tid < 64) xred[tid] = 0.f;
            if (mx == 0) {
                if (t >= 1 && tid < 64) {
                    // out[:, t-1] = xacc[(t-1)%3] + lin_b  (complete after prev barrier)
                    float v = xacc[((t - 1) % 3) * BATCH + nbase + tid] + lb;
                    out[(size_t)(nbase + tid) * TOUT + (t - 1)] = v;
                }
                if (tid >= 64 && tid < 128) {
                    // zero buffer (t+1)%3: its readers ran at step t-1, next accum at t+1
                    xacc[((t + 1) % 3) * BATCH + nbase + (tid - 64)] = 0.f;
                }
            }
            #pragma unroll
            for (int nt = 0; nt < 4; ++nt)
                xq[nt] = (t == 0) ? inputsT[(TIN - 1) * BATCH + bn[nt]]
                                  : xacc[((t - 1) % 3) * BATCH + bn[nt]] + lb;
        } else {
            #pragma unroll
            for (int nt = 0; nt < 4; ++nt)
                xq[nt] = inputsT[s * BATCH + bn[nt]];
        }

        // ---- K-loop: Z = W'.(Hhi+Hlo), 3-product bf16 split, A from LDS ----
        floatx4 acc0 = {0,0,0,0}, acc1 = {0,0,0,0}, acc2 = {0,0,0,0}, acc3 = {0,0,0,0};
        const __bf16* b0h = hinhi + (size_t)bn[0] * HID + lq * 8;
        const __bf16* b1h = hinhi + (size_t)bn[1] * HID + lq * 8;
        const __bf16* b2h = hinhi + (size_t)bn[2] * HID + lq * 8;
        const __bf16* b3h = hinhi + (size_t)bn[3] * HID + lq * 8;
        const __bf16* b0l = hinlo + (size_t)bn[0] * HID + lq * 8;
        const __bf16* b1l = hinlo + (size_t)bn[1] * HID + lq * 8;
        const __bf16* b2l = hinlo + (size_t)bn[2] * HID + lq * 8;
        const __bf16* b3l = hinlo + (size_t)bn[3] * HID + lq * 8;

        #pragma unroll
        for (int kc = 0; kc < HID; kc += 32) {
            bf16x8 ah  = *(const bf16x8*)(aHi_p + kc);
            bf16x8 al  = *(const bf16x8*)(aLo_p + kc);
            bf16x8 bh0 = *(const bf16x8*)(b0h + kc);
            bf16x8 bh1 = *(const bf16x8*)(b1h + kc);
            bf16x8 bh2 = *(const bf16x8*)(b2h + kc);
            bf16x8 bh3 = *(const bf16x8*)(b3h + kc);
            bf16x8 bl0 = *(const bf16x8*)(b0l + kc);
            bf16x8 bl1 = *(const bf16x8*)(b1l + kc);
            bf16x8 bl2 = *(const bf16x8*)(b2l + kc);
            bf16x8 bl3 = *(const bf16x8*)(b3l + kc);

            acc0 = __builtin_amdgcn_mfma_f32_16x16x32_bf16(ah, bh0, acc0, 0, 0, 0);
            acc1 = __builtin_amdgcn_mfma_f32_16x16x32_bf16(ah, bh1, acc1, 0, 0, 0);
            acc2 = __builtin_amdgcn_mfma_f32_16x16x32_bf16(ah, bh2, acc2, 0, 0, 0);
            acc3 = __builtin_amdgcn_mfma_f32_16x16x32_bf16(ah, bh3, acc3, 0, 0, 0);
            acc0 = __builtin_amdgcn_mfma_f32_16x16x32_bf16(al, bh0, acc0, 0, 0, 0);
            acc1 = __builtin_amdgcn_mfma_f32_16x16x32_bf16(al, bh1, acc1, 0, 0, 0);
            acc2 = __builtin_amdgcn_mfma_f32_16x16x32_bf16(al, bh2, acc2, 0, 0, 0);
            acc3 = __builtin_amdgcn_mfma_f32_16x16x32_bf16(al, bh3, acc3, 0, 0, 0);
            acc0 = __builtin_amdgcn_mfma_f32_16x16x32_bf16(ah, bl0, acc0, 0, 0, 0);
            acc1 = __builtin_amdgcn_mfma_f32_16x16x32_bf16(ah, bl1, acc1, 0, 0, 0);
            acc2 = __builtin_amdgcn_mfma_f32_16x16x32_bf16(ah, bl2, acc2, 0, 0, 0);
            acc3 = __builtin_amdgcn_mfma_f32_16x16x32_bf16(ah, bl3, acc3, 0, 0, 0);
        }

        // ---- epilogue: gates, c update (regs), h split-store ----
        const floatx4 wih = dec ? wihD : wihE;
        const floatx4 bb  = dec ? bD   : bE;
        floatx4 accs[4] = {acc0, acc1, acc2, acc3};
        float hv[4];
        #pragma unroll
        for (int nt = 0; nt < 4; ++nt) {
            float x  = xq[nt];
            float i_ = fsig (accs[nt][0] + bb[0] + x * wih[0]);
            float f_ = fsig (accs[nt][1] + bb[1] + x * wih[1]);
            float g_ = ftanh(accs[nt][2] + bb[2] + x * wih[2]);
            float o_ = fsig (accs[nt][3] + bb[3] + x * wih[3]);
            float cv = f_ * creg[nt] + i_ * g_;
            creg[nt] = cv;
            float h  = o_ * ftanh(cv);
            hv[nt] = h;
            __bf16 hh = (__bf16)h;
            houthi[(size_t)bn[nt] * HID + j] = hh;
            houtlo[(size_t)bn[nt] * HID + j] = (__bf16)(h - (float)hh);
        }

        // ---- decoder: accumulate this block's 16-j slice of h . linW into xacc[t%3]
        if (dec) {
            float px[4];
            #pragma unroll
            for (int nt = 0; nt < 4; ++nt) {
                float v = hv[nt] * lw;
                v += __shfl_xor(v, 16);
                v += __shfl_xor(v, 32);   // lanes 0..15 hold sum over lq for this wave
                px[nt] = v;
            }
            __syncthreads();              // xred zeroing (loop top) visible
            if (lane < 16) {
                #pragma unroll
                for (int nt = 0; nt < 4; ++nt) atomicAdd(&xred[nt * 16 + lr], px[nt]);
            }
            __syncthreads();
            if (tid < 64) atomicAdd(&xacc[(t % 3) * BATCH + nbase + tid], xred[tid]);
        }

        // ---- group barrier (32 blocks sharing `by`) ----
        __threadfence();                  // per-wave: drain + write back h stores
        __syncthreads();
        if (tid == 0) {
            int n = __hip_atomic_fetch_add(&arrive[0], 1, __ATOMIC_ACQ_REL, __HIP_MEMORY_SCOPE_AGENT);
            if (n == 32 * (s + 1) - 1) {
                __hip_atomic_store(&phase[0], s + 1, __ATOMIC_RELEASE, __HIP_MEMORY_SCOPE_AGENT);
            } else {
                while (__hip_atomic_load(&phase[0], __ATOMIC_ACQUIRE, __HIP_MEMORY_SCOPE_AGENT) < s + 1) {}
            }
        }
        __syncthreads();
    }

    // tail: out[:, TOUT-1]
    if (mx == 0 && tid < 64) {
        float v = xacc[((TOUT - 1) % 3) * BATCH + nbase + tid] + lb;
        out[(size_t)(nbase + tid) * TOUT + (TOUT - 1)] = v;
    }
}

extern "C" void kernel_launch(void* const* d_in, const int* in_sizes, int n_in,
                              void* d_out, int out_size, void* d_ws, size_t ws_size,
                              hipStream_t stream) {
    const float* inputs  = (const float*)d_in[0];
    const float* enc_Wih = (const float*)d_in[2];
    const float* enc_Whh = (const float*)d_in[3];
    const float* enc_b   = (const float*)d_in[4];
    const float* dec_Wih = (const float*)d_in[5];
    const float* dec_Whh = (const float*)d_in[6];
    const float* dec_b   = (const float*)d_in[7];
    const float* lin_W   = (const float*)d_in[8];
    const float* lin_b   = (const float*)d_in[9];
    float* out = (float*)d_out;

    char* ws = (char*)d_ws;
    const size_t SZ_A = (size_t)FOUR_H * HID * sizeof(__bf16);  // 2 MB
    const size_t SZ_V = (size_t)FOUR_H * sizeof(float);         // 8 KB
    const size_t SZ_H = (size_t)BATCH * HID * sizeof(__bf16);   // 512 KB

    __bf16* AencHi = (__bf16*)(ws);
    __bf16* AencLo = (__bf16*)(ws + SZ_A);
    __bf16* AdecHi = (__bf16*)(ws + 2 * SZ_A);
    __bf16* AdecLo = (__bf16*)(ws + 3 * SZ_A);
    char* p = ws + 4 * SZ_A;
    float* WihPenc  = (float*)p;  p += SZ_V;
    float* biasPenc = (float*)p;  p += SZ_V;
    float* WihPdec  = (float*)p;  p += SZ_V;
    float* biasPdec = (float*)p;  p += SZ_V;
    float* inputsT  = (float*)p;  p += (size_t)TIN * BATCH * sizeof(float);  // 1 MB
    __bf16* h0hi = (__bf16*)p;    p += SZ_H;
    __bf16* h0lo = (__bf16*)p;    p += SZ_H;
    __bf16* h1hi = (__bf16*)p;    p += SZ_H;
    __bf16* h1lo = (__bf16*)p;    p += SZ_H;
    float* xacc  = (float*)p;     p += 3 * BATCH * sizeof(float);
    int* barrier_ws = (int*)p;    p += 1024 * sizeof(int);

    // prep (every call; ws is re-poisoned before every timed launch)
    pack_w<<<512, 256, 0, stream>>>(enc_Whh, AencHi, AencLo);
    pack_w<<<512, 256, 0, stream>>>(dec_Whh, AdecHi, AdecLo);
    pack_v<<<8, 256, 0, stream>>>(enc_Wih, enc_b, WihPenc, biasPenc);
    pack_v<<<8, 256, 0, stream>>>(dec_Wih, dec_b, WihPdec, biasPdec);
    transpose_in<<<1024, 256, 0, stream>>>(inputs, inputsT);
    hipMemsetAsync(h0hi, 0, SZ_H, stream);
    hipMemsetAsync(h0lo, 0, SZ_H, stream);
    hipMemsetAsync(xacc, 0, 3 * BATCH * sizeof(float), stream);
    hipMemsetAsync(barrier_ws, 0, 1024 * sizeof(int), stream);

    const int shmem = (64 * LDS_STRIDE * 2 * 2) + 64 * 4;   // 133376 B
    static bool attr_set = false;
    hipFuncSetAttribute((const void*)lstm_persistent,
                        hipFuncAttributeMaxDynamicSharedMemorySize, shmem);
    (void)attr_set;

    void* args[] = {
        (void*)&AencHi, (void*)&AencLo, (void*)&AdecHi, (void*)&AdecLo,
        (void*)&WihPenc, (void*)&biasPenc, (void*)&WihPdec, (void*)&biasPdec,
        (void*)&inputsT, (void*)&lin_W, (void*)&lin_b,
        (void*)&h0hi, (void*)&h0lo, (void*)&h1hi, (void*)&h1lo,
        (void*)&xacc, (void*)&barrier_ws, (void*)&out
    };
    hipLaunchCooperativeKernel((void*)lstm_persistent, dim3(256), dim3(256),
                               args, shmem, stream);
}

// Round 4
// 10738.758 us; speedup vs baseline: 3.1972x; 3.1972x over previous
//
#include <hip/hip_runtime.h>
#include <math.h>

#define HID    512
#define BATCH  512
#define TIN    512
#define TOUT   128
#define FOUR_H 2048
#define STEPS  (TIN + TOUT)
#define LDS_STRIDE 520   // elements; 1040 B/row

typedef __bf16 bf16x8 __attribute__((ext_vector_type(8)));
typedef float floatx4 __attribute__((ext_vector_type(4)));
typedef int   int4v   __attribute__((ext_vector_type(4)));

// LLC-direct (bypass L1+L2) 16-B load/store; waitcnt tied through operands so
// the compiler cannot reorder MFMA consumption ahead of data arrival.
#define GLOADX4(dst, p) \
    asm volatile("global_load_dwordx4 %0, %1, off sc0 sc1" : "=v"(dst) : "v"(p))
#define GSTOREX4(p, v) \
    asm volatile("global_store_dwordx4 %0, %1, off sc0 sc1" :: "v"(p), "v"(v) : "memory")
#define WAITV(N, B) \
    asm volatile("s_waitcnt vmcnt(" #N ")" \
        : "+v"((B)[0]), "+v"((B)[1]), "+v"((B)[2]), "+v"((B)[3]), \
          "+v"((B)[4]), "+v"((B)[5]), "+v"((B)[6]), "+v"((B)[7]))

__device__ __forceinline__ float fsig(float x) {
    return __builtin_amdgcn_rcpf(1.0f + __expf(-x));
}
__device__ __forceinline__ float ftanh(float x) {
    return 1.0f - 2.0f * __builtin_amdgcn_rcpf(1.0f + __expf(2.0f * x));
}

// pack Whh (4H x H fp32, row r = g*512+j) into m' = 4*j + g order, bf16 hi/lo
// (numerics verified R2/R3: absmax ~1e-7)
__global__ __launch_bounds__(256) void pack_w(
    const float* __restrict__ W, __bf16* __restrict__ outHi, __bf16* __restrict__ outLo)
{
    int tid = blockIdx.x * 256 + threadIdx.x;
    int mp  = tid >> 6;
    int kg  = (tid & 63) * 8;
    int g   = mp & 3;
    int j   = mp >> 2;
    int r   = g * HID + j;
    const float* src = W + (size_t)r * HID + kg;
    __bf16* dh = outHi + (size_t)mp * HID + kg;
    __bf16* dl = outLo + (size_t)mp * HID + kg;
    #pragma unroll
    for (int i = 0; i < 8; ++i) {
        float x = src[i];
        __bf16 hi = (__bf16)x;
        dh[i] = hi;
        dl[i] = (__bf16)(x - (float)hi);
    }
}

__global__ __launch_bounds__(256) void pack_v(
    const float* __restrict__ Wih, const float* __restrict__ b,
    float* __restrict__ WihP, float* __restrict__ bP)
{
    int mp = blockIdx.x * 256 + threadIdx.x;
    int g  = mp & 3;
    int j  = mp >> 2;
    int r  = g * HID + j;
    WihP[mp] = Wih[r];
    bP[mp]   = b[r];
}

__global__ __launch_bounds__(256) void transpose_in(
    const float* __restrict__ in, float* __restrict__ outT)
{
    int idx = blockIdx.x * 256 + threadIdx.x;
    int t = idx >> 9, b = idx & 511;
    outT[idx] = in[(size_t)b * TIN + t];
}

// ---------- persistent cooperative kernel ----------
// grid 256 = 32 mx x 8 by; block 256 = 4 waves. No fences anywhere: h exchange
// is LLC-direct (sc0 sc1), barrier is relaxed device-scope atomics.
__global__ __launch_bounds__(256, 1) void lstm_persistent(
    const __bf16* __restrict__ AencHi, const __bf16* __restrict__ AencLo,
    const __bf16* __restrict__ AdecHi, const __bf16* __restrict__ AdecLo,
    const float* __restrict__ WihPenc, const float* __restrict__ biasPenc,
    const float* __restrict__ WihPdec, const float* __restrict__ biasPdec,
    const float* __restrict__ inputsT,
    const float* __restrict__ linW, const float* __restrict__ linb,
    __bf16* __restrict__ h0hi, __bf16* __restrict__ h0lo,
    __bf16* __restrict__ h1hi, __bf16* __restrict__ h1lo,
    float* __restrict__ xacc,        // [3][BATCH] rotating decoder-feedback accum
    int* __restrict__ barrier_ws,    // arrive at by*32, phase at 512+by*32
    float* __restrict__ out)         // [BATCH][TOUT]
{
    extern __shared__ char smem[];
    __bf16* Ahi = (__bf16*)smem;                       // [64][LDS_STRIDE]
    __bf16* Alo = Ahi + 64 * LDS_STRIDE;
    __bf16* hstage = (__bf16*)(smem + 64 * LDS_STRIDE * 2 * 2);  // [2][64][16]
    float*  xred = (float*)(smem + 64 * LDS_STRIDE * 2 * 2 + 4096); // [64]

    const int tid  = threadIdx.x;
    const int lane = tid & 63;
    const int w    = tid >> 6;
    const int lr   = lane & 15;
    const int lq   = lane >> 4;
    const int by   = blockIdx.x & 7;
    const int mx   = blockIdx.x >> 3;
    const int nbase = by * 64;
    const int mrow0 = mx * 64;
    const int m0    = mrow0 + w * 16 + lq * 4;   // lane's 4 m' rows = 4 gates of j
    const int jl    = w * 4 + lq;                // local j index 0..15

    const floatx4 wihE = *(const floatx4*)(WihPenc + m0);
    const floatx4 bE   = *(const floatx4*)(biasPenc + m0);
    const floatx4 wihD = *(const floatx4*)(WihPdec + m0);
    const floatx4 bD   = *(const floatx4*)(biasPdec + m0);
    const float lw = linW[mx * 16 + jl];
    const float lb = linb[0];

    int bn[4];
    #pragma unroll
    for (int nt = 0; nt < 4; ++nt) bn[nt] = nbase + nt * 16 + lr;

    // stage encoder weights into LDS (normal cached loads; read-only data)
    for (int i = tid; i < 4096; i += 256) {
        int r = i >> 6, c8 = (i & 63) << 3;
        *(bf16x8*)(Ahi + r * LDS_STRIDE + c8) = *(const bf16x8*)(AencHi + (size_t)(mrow0 + r) * HID + c8);
        *(bf16x8*)(Alo + r * LDS_STRIDE + c8) = *(const bf16x8*)(AencLo + (size_t)(mrow0 + r) * HID + c8);
    }
    __syncthreads();

    float creg[4] = {0.f, 0.f, 0.f, 0.f};

    int* arrive = barrier_ws + by * 32;
    int* phase  = barrier_ws + 512 + by * 32;

    const __bf16* aHi_p = Ahi + (w * 16 + lr) * LDS_STRIDE + lq * 8;
    const __bf16* aLo_p = Alo + (w * 16 + lr) * LDS_STRIDE + lq * 8;

    for (int s = 0; s < STEPS; ++s) {
        const bool dec = (s >= TIN);
        const int  t   = s - TIN;

        if (s == TIN) {
            for (int i = tid; i < 4096; i += 256) {
                int r = i >> 6, c8 = (i & 63) << 3;
                *(bf16x8*)(Ahi + r * LDS_STRIDE + c8) = *(const bf16x8*)(AdecHi + (size_t)(mrow0 + r) * HID + c8);
                *(bf16x8*)(Alo + r * LDS_STRIDE + c8) = *(const bf16x8*)(AdecLo + (size_t)(mrow0 + r) * HID + c8);
            }
            __syncthreads();
        }

        const __bf16* hinhi = (s & 1) ? h1hi : h0hi;
        const __bf16* hinlo = (s & 1) ? h1lo : h0lo;
        __bf16* houthi = (s & 1) ? h0hi : h1hi;
        __bf16* houtlo = (s & 1) ? h0lo : h1lo;

        // ---- x_t + decoder bookkeeping ----
        float xq[4];
        if (dec) {
            if (tid < 64) xred[tid] = 0.f;
            if (mx == 0) {
                if (t >= 1 && tid < 64) {
                    float v = __hip_atomic_load(&xacc[((t - 1) % 3) * BATCH + nbase + tid],
                                                __ATOMIC_RELAXED, __HIP_MEMORY_SCOPE_AGENT) + lb;
                    out[(size_t)(nbase + tid) * TOUT + (t - 1)] = v;
                }
                if (tid >= 64 && tid < 128) {
                    __hip_atomic_store(&xacc[((t + 1) % 3) * BATCH + nbase + (tid - 64)], 0.0f,
                                       __ATOMIC_RELAXED, __HIP_MEMORY_SCOPE_AGENT);
                }
            }
            #pragma unroll
            for (int nt = 0; nt < 4; ++nt)
                xq[nt] = (t == 0) ? inputsT[(TIN - 1) * BATCH + bn[nt]]
                                  : __hip_atomic_load(&xacc[((t - 1) % 3) * BATCH + bn[nt]],
                                                      __ATOMIC_RELAXED, __HIP_MEMORY_SCOPE_AGENT) + lb;
        } else {
            #pragma unroll
            for (int nt = 0; nt < 4; ++nt)
                xq[nt] = inputsT[s * BATCH + bn[nt]];
        }

        // ---- K-loop: LLC-direct B loads, software-pipelined; A from LDS ----
        const __bf16* pB[8];
        #pragma unroll
        for (int nt = 0; nt < 4; ++nt) {
            pB[2 * nt]     = hinhi + (size_t)bn[nt] * HID + lq * 8;
            pB[2 * nt + 1] = hinlo + (size_t)bn[nt] * HID + lq * 8;
        }

        int4v bufA[8], bufB[8];
        #pragma unroll
        for (int i = 0; i < 8; ++i) GLOADX4(bufA[i], pB[i]);
        #pragma unroll
        for (int i = 0; i < 8; ++i) pB[i] += 32;

        floatx4 acc0 = {0,0,0,0}, acc1 = {0,0,0,0}, acc2 = {0,0,0,0}, acc3 = {0,0,0,0};

        #pragma unroll
        for (int it = 0; it < 16; ++it) {
            int4v* cur = (it & 1) ? bufB : bufA;
            int4v* nxt = (it & 1) ? bufA : bufB;
            if (it < 15) {
                #pragma unroll
                for (int i = 0; i < 8; ++i) GLOADX4(nxt[i], pB[i]);
                #pragma unroll
                for (int i = 0; i < 8; ++i) pB[i] += 32;
                WAITV(8, cur);
            } else {
                WAITV(0, cur);
            }
            const int kc = it * 32;
            bf16x8 ah = *(const bf16x8*)(aHi_p + kc);
            bf16x8 al = *(const bf16x8*)(aLo_p + kc);
            bf16x8 bh0 = __builtin_bit_cast(bf16x8, cur[0]);
            bf16x8 bl0 = __builtin_bit_cast(bf16x8, cur[1]);
            bf16x8 bh1 = __builtin_bit_cast(bf16x8, cur[2]);
            bf16x8 bl1 = __builtin_bit_cast(bf16x8, cur[3]);
            bf16x8 bh2 = __builtin_bit_cast(bf16x8, cur[4]);
            bf16x8 bl2 = __builtin_bit_cast(bf16x8, cur[5]);
            bf16x8 bh3 = __builtin_bit_cast(bf16x8, cur[6]);
            bf16x8 bl3 = __builtin_bit_cast(bf16x8, cur[7]);

            acc0 = __builtin_amdgcn_mfma_f32_16x16x32_bf16(ah, bh0, acc0, 0, 0, 0);
            acc1 = __builtin_amdgcn_mfma_f32_16x16x32_bf16(ah, bh1, acc1, 0, 0, 0);
            acc2 = __builtin_amdgcn_mfma_f32_16x16x32_bf16(ah, bh2, acc2, 0, 0, 0);
            acc3 = __builtin_amdgcn_mfma_f32_16x16x32_bf16(ah, bh3, acc3, 0, 0, 0);
            acc0 = __builtin_amdgcn_mfma_f32_16x16x32_bf16(al, bh0, acc0, 0, 0, 0);
            acc1 = __builtin_amdgcn_mfma_f32_16x16x32_bf16(al, bh1, acc1, 0, 0, 0);
            acc2 = __builtin_amdgcn_mfma_f32_16x16x32_bf16(al, bh2, acc2, 0, 0, 0);
            acc3 = __builtin_amdgcn_mfma_f32_16x16x32_bf16(al, bh3, acc3, 0, 0, 0);
            acc0 = __builtin_amdgcn_mfma_f32_16x16x32_bf16(ah, bl0, acc0, 0, 0, 0);
            acc1 = __builtin_amdgcn_mfma_f32_16x16x32_bf16(ah, bl1, acc1, 0, 0, 0);
            acc2 = __builtin_amdgcn_mfma_f32_16x16x32_bf16(ah, bl2, acc2, 0, 0, 0);
            acc3 = __builtin_amdgcn_mfma_f32_16x16x32_bf16(ah, bl3, acc3, 0, 0, 0);
        }

        // ---- epilogue: gates, c in regs, stage h tile to LDS ----
        const floatx4 wih = dec ? wihD : wihE;
        const floatx4 bb  = dec ? bD   : bE;
        floatx4 accs[4] = {acc0, acc1, acc2, acc3};
        float px[4];
        #pragma unroll
        for (int nt = 0; nt < 4; ++nt) {
            float x  = xq[nt];
            float i_ = fsig (accs[nt][0] + bb[0] + x * wih[0]);
            float f_ = fsig (accs[nt][1] + bb[1] + x * wih[1]);
            float g_ = ftanh(accs[nt][2] + bb[2] + x * wih[2]);
            float o_ = fsig (accs[nt][3] + bb[3] + x * wih[3]);
            float cv = f_ * creg[nt] + i_ * g_;
            creg[nt] = cv;
            float h  = o_ * ftanh(cv);
            __bf16 hh = (__bf16)h;
            int bl = nt * 16 + lr;
            hstage[bl * 16 + jl] = hh;
            hstage[1024 + bl * 16 + jl] = (__bf16)(h - (float)hh);
            if (dec) {
                float v = h * lw;
                v += __shfl_xor(v, 16);
                v += __shfl_xor(v, 32);
                px[nt] = v;
            }
        }

        __syncthreads();   // hstage complete; xred zero visible

        // coalesced LLC-direct h store: 16-B chunk per thread
        {
            int plane = tid >> 7;
            int q = tid & 127;
            int b2 = q >> 1, half = q & 1;
            const __bf16* src = hstage + plane * 1024 + b2 * 16 + half * 8;
            int4v v = *(const int4v*)src;
            __bf16* base = plane ? houtlo : houthi;
            __bf16* dst = base + (size_t)(nbase + b2) * HID + mx * 16 + half * 8;
            GSTOREX4(dst, v);
        }

        if (dec && lane < 16) {
            #pragma unroll
            for (int nt = 0; nt < 4; ++nt) atomicAdd(&xred[nt * 16 + lr], px[nt]);
        }
        __syncthreads();   // xred final; hstage reads done
        if (dec && tid < 64) {
            atomicAdd(&xacc[(t % 3) * BATCH + nbase + tid], xred[tid]);
        }

        // ---- group barrier: relaxed device-scope atomics, no fences ----
        __builtin_amdgcn_s_waitcnt(0);   // all this wave's stores/atomics at LLC
        __syncthreads();
        if (tid == 0) {
            int n = __hip_atomic_fetch_add(arrive, 1, __ATOMIC_RELAXED, __HIP_MEMORY_SCOPE_AGENT);
            if (n == 32 * (s + 1) - 1) {
                __hip_atomic_store(phase, s + 1, __ATOMIC_RELAXED, __HIP_MEMORY_SCOPE_AGENT);
            } else {
                int p;
                do {
                    __builtin_amdgcn_s_sleep(2);
                    p = __hip_atomic_load(phase, __ATOMIC_RELAXED, __HIP_MEMORY_SCOPE_AGENT);
                } while (p < s + 1);
            }
        }
        __syncthreads();
    }

    // tail: out[:, TOUT-1]
    if (mx == 0 && tid < 64) {
        float v = __hip_atomic_load(&xacc[((TOUT - 1) % 3) * BATCH + nbase + tid],
                                    __ATOMIC_RELAXED, __HIP_MEMORY_SCOPE_AGENT) + lb;
        out[(size_t)(nbase + tid) * TOUT + (TOUT - 1)] = v;
    }
}

extern "C" void kernel_launch(void* const* d_in, const int* in_sizes, int n_in,
                              void* d_out, int out_size, void* d_ws, size_t ws_size,
                              hipStream_t stream) {
    const float* inputs  = (const float*)d_in[0];
    const float* enc_Wih = (const float*)d_in[2];
    const float* enc_Whh = (const float*)d_in[3];
    const float* enc_b   = (const float*)d_in[4];
    const float* dec_Wih = (const float*)d_in[5];
    const float* dec_Whh = (const float*)d_in[6];
    const float* dec_b   = (const float*)d_in[7];
    const float* lin_W   = (const float*)d_in[8];
    const float* lin_b   = (const float*)d_in[9];
    float* out = (float*)d_out;

    char* ws = (char*)d_ws;
    const size_t SZ_A = (size_t)FOUR_H * HID * sizeof(__bf16);  // 2 MB
    const size_t SZ_V = (size_t)FOUR_H * sizeof(float);
    const size_t SZ_H = (size_t)BATCH * HID * sizeof(__bf16);   // 512 KB

    __bf16* AencHi = (__bf16*)(ws);
    __bf16* AencLo = (__bf16*)(ws + SZ_A);
    __bf16* AdecHi = (__bf16*)(ws + 2 * SZ_A);
    __bf16* AdecLo = (__bf16*)(ws + 3 * SZ_A);
    char* p = ws + 4 * SZ_A;
    float* WihPenc  = (float*)p;  p += SZ_V;
    float* biasPenc = (float*)p;  p += SZ_V;
    float* WihPdec  = (float*)p;  p += SZ_V;
    float* biasPdec = (float*)p;  p += SZ_V;
    float* inputsT  = (float*)p;  p += (size_t)TIN * BATCH * sizeof(float);
    __bf16* h0hi = (__bf16*)p;    p += SZ_H;
    __bf16* h0lo = (__bf16*)p;    p += SZ_H;
    __bf16* h1hi = (__bf16*)p;    p += SZ_H;
    __bf16* h1lo = (__bf16*)p;    p += SZ_H;
    float* xacc  = (float*)p;     p += 3 * BATCH * sizeof(float);
    int* barrier_ws = (int*)p;    p += 1024 * sizeof(int);

    pack_w<<<512, 256, 0, stream>>>(enc_Whh, AencHi, AencLo);
    pack_w<<<512, 256, 0, stream>>>(dec_Whh, AdecHi, AdecLo);
    pack_v<<<8, 256, 0, stream>>>(enc_Wih, enc_b, WihPenc, biasPenc);
    pack_v<<<8, 256, 0, stream>>>(dec_Wih, dec_b, WihPdec, biasPdec);
    transpose_in<<<1024, 256, 0, stream>>>(inputs, inputsT);
    hipMemsetAsync(h0hi, 0, SZ_H, stream);
    hipMemsetAsync(h0lo, 0, SZ_H, stream);
    hipMemsetAsync(xacc, 0, 3 * BATCH * sizeof(float), stream);
    hipMemsetAsync(barrier_ws, 0, 1024 * sizeof(int), stream);

    const int shmem = 64 * LDS_STRIDE * 2 * 2 + 4096 + 256;   // A + hstage + xred
    hipFuncSetAttribute((const void*)lstm_persistent,
                        hipFuncAttributeMaxDynamicSharedMemorySize, shmem);

    void* args[] = {
        (void*)&AencHi, (void*)&AencLo, (void*)&AdecHi, (void*)&AdecLo,
        (void*)&WihPenc, (void*)&biasPenc, (void*)&WihPdec, (void*)&biasPdec,
        (void*)&inputsT, (void*)&lin_W, (void*)&lin_b,
        (void*)&h0hi, (void*)&h0lo, (void*)&h1hi, (void*)&h1lo,
        (void*)&xacc, (void*)&barrier_ws, (void*)&out
    };
    hipLaunchCooperativeKernel((void*)lstm_persistent, dim3(256), dim3(256),
                               args, shmem, stream);
}